// Round 1
// baseline (1365.842 us; speedup 1.0000x reference)
//
#include <hip/hip_runtime.h>

#define B_ 8
#define S_ 1024
#define E_ 1024
#define H_ 16
#define D_ 64

typedef __attribute__((ext_vector_type(8))) short bf16x8;
typedef __attribute__((ext_vector_type(4))) float floatx4;

__device__ __forceinline__ floatx4 mfma16x16x32(bf16x8 a, bf16x8 b, floatx4 c) {
  return __builtin_amdgcn_mfma_f32_16x16x32_bf16(a, b, c, 0, 0, 0);
}

// f32 -> bf16 round-to-nearest-even, dependency-free bit trick
__device__ __forceinline__ unsigned short f2bf(float x) {
  unsigned int u = __builtin_bit_cast(unsigned int, x);
  u += 0x7FFFu + ((u >> 16) & 1u);
  return (unsigned short)(u >> 16);
}

// ---------------------------------------------------------------------------
// Kernel 1: detect key_padding_mask storage (bool bytes / int32 / float32)
// and normalize to additive mask: 0.0 or -FLT_MAX (== jnp.finfo(f32).min).
// Reads only the first 8192 bytes (valid under every encoding).
// ---------------------------------------------------------------------------
__global__ void mask_prep(const unsigned int* __restrict__ mraw, float* __restrict__ maskadd) {
  __shared__ int flagF, flagB;
  const int tid = threadIdx.x;
  if (tid == 0) { flagF = 0; flagB = 0; }
  __syncthreads();
  int lf = 0, lb = 0;
  for (int i = tid; i < 2048; i += 256) {  // 2048 uints = 8192 bytes, safe for all encodings
    unsigned int v = mraw[i];
    if (v == 0x3F800000u) lf = 1;          // float 1.0f present -> float storage
    else if (v > 1u) lb = 1;               // packed 0/1 bytes -> byte (bool) storage
  }
  if (lf) atomicOr(&flagF, 1);
  if (lb) atomicOr(&flagB, 1);
  __syncthreads();
  const unsigned char* mb = (const unsigned char*)mraw;
  const float* mf = (const float*)mraw;
  const int* mi = (const int*)mraw;
  const int fF = flagF, fB = flagB;
  for (int i = tid; i < B_ * S_; i += 256) {
    int pad;
    if (fF)      pad = (mf[i] != 0.0f);
    else if (fB) pad = (mb[i] != 0);
    else         pad = (mi[i] != 0);
    maskadd[i] = pad ? -3.4028234663852886e38f : 0.0f;
  }
}

// ---------------------------------------------------------------------------
// Kernel 2: fused QKV projection.  out = X @ W.T + b  for W in {Wq,Wk,Wv}.
// M=8192 (b*S+s), K=1024, N=3072 (q|k|v concat; each 128-col tile lies in one).
// 128x128 block tile, 4 waves in 2x2, each wave 4x4 frags of 16x16x32 bf16 MFMA.
// LDS rows padded to 40 bf16 (80 B) -> conflict-free quad-strided ds_read_b128.
// Epilogue: q,k stored bf16 [B,H,S,D]; v stored bf16 TRANSPOSED [B,H,D,S].
// q gets * D^-0.5 after bias, matching reference.
// ---------------------------------------------------------------------------
__global__ __launch_bounds__(256) void gemm_qkv(
    const float* __restrict__ X,
    const float* __restrict__ Wq, const float* __restrict__ Wk, const float* __restrict__ Wv,
    const float* __restrict__ bq, const float* __restrict__ bk, const float* __restrict__ bv,
    unsigned short* __restrict__ qo, unsigned short* __restrict__ ko, unsigned short* __restrict__ vo)
{
  const int tid = threadIdx.x;
  const int n0 = blockIdx.x * 128;
  const int m0 = blockIdx.y * 128;
  const int which = n0 >> 10;          // 0:q 1:k 2:v (uniform per block)
  const int nn0 = n0 & 1023;
  const float* W    = (which == 0) ? Wq : (which == 1) ? Wk : Wv;
  const float* bias = (which == 0) ? bq : (which == 1) ? bk : bv;

  __shared__ unsigned short As[128 * 40];
  __shared__ unsigned short Bs[128 * 40];

  const int wave = tid >> 6;
  const int lane = tid & 63;
  const int quad = lane >> 4;
  const int l16  = lane & 15;
  const int mb = (wave >> 1) * 64;
  const int nb = (wave & 1) * 64;

  floatx4 z = {0.f, 0.f, 0.f, 0.f};
  floatx4 acc[4][4];
  for (int i = 0; i < 4; ++i) for (int j = 0; j < 4; ++j) acc[i][j] = z;

  for (int ks = 0; ks < 32; ++ks) {
    const int k0 = ks * 32;
    __syncthreads();
    for (int i = tid; i < 1024; i += 256) {        // A tile: 128 rows x 32 k
      int row = i >> 3, kq = i & 7;
      float4 v = *(const float4*)(X + (size_t)(m0 + row) * 1024 + k0 + kq * 4);
      ushort4 u; u.x = f2bf(v.x); u.y = f2bf(v.y); u.z = f2bf(v.z); u.w = f2bf(v.w);
      *(ushort4*)(&As[row * 40 + kq * 4]) = u;
    }
    for (int i = tid; i < 1024; i += 256) {        // B tile: 128 out-cols x 32 k
      int row = i >> 3, kq = i & 7;
      float4 v = *(const float4*)(W + (size_t)(nn0 + row) * 1024 + k0 + kq * 4);
      ushort4 u; u.x = f2bf(v.x); u.y = f2bf(v.y); u.z = f2bf(v.z); u.w = f2bf(v.w);
      *(ushort4*)(&Bs[row * 40 + kq * 4]) = u;
    }
    __syncthreads();
    bf16x8 af[4], bfm[4];
    for (int i = 0; i < 4; ++i)
      af[i] = *(const bf16x8*)(&As[(mb + 16 * i + l16) * 40 + quad * 8]);
    for (int j = 0; j < 4; ++j)
      bfm[j] = *(const bf16x8*)(&Bs[(nb + 16 * j + l16) * 40 + quad * 8]);
    for (int i = 0; i < 4; ++i)
      for (int j = 0; j < 4; ++j)
        acc[i][j] = mfma16x16x32(af[i], bfm[j], acc[i][j]);
  }

  float bv4[4];
  for (int j = 0; j < 4; ++j) bv4[j] = bias[nn0 + nb + 16 * j + l16];

  for (int i = 0; i < 4; ++i) {
    for (int r = 0; r < 4; ++r) {
      int m = m0 + mb + 16 * i + quad * 4 + r;     // C/D: row = quad*4+reg
      int bb = m >> 10, s = m & 1023;
      for (int j = 0; j < 4; ++j) {
        int nn = nn0 + nb + 16 * j + l16;          // C/D: col = lane&15
        int hh = nn >> 6, d = nn & 63;
        float val = acc[i][j][r] + bv4[j];
        if (which == 0) {
          val *= 0.125f;                           // D^-0.5
          qo[((size_t)(bb * 16 + hh) * 1024 + s) * 64 + d] = f2bf(val);
        } else if (which == 1) {
          ko[((size_t)(bb * 16 + hh) * 1024 + s) * 64 + d] = f2bf(val);
        } else {
          vo[((size_t)(bb * 16 + hh) * 64 + d) * 1024 + s] = f2bf(val);  // v^T
        }
      }
    }
  }
}

// ---------------------------------------------------------------------------
// Kernel 3: flash attention.  Grid (16 q-tiles, 128 bh).  Block = 4 waves;
// each wave owns 16 q rows.  K-tiles of 64 keys: S = Q K^T via MFMA (K frags
// straight from global; L3-resident), + bias + attn_mask + padding mask,
// online softmax (shuffle reductions within 16-lane quads), P -> bf16 via
// per-wave LDS (C-layout -> A-layout), O += P V via MFMA with v^T B-operand.
// ---------------------------------------------------------------------------
__global__ __launch_bounds__(256) void attn_fwd(
    const unsigned short* __restrict__ qw, const unsigned short* __restrict__ kw,
    const unsigned short* __restrict__ vw, const float* __restrict__ bias,
    const float* __restrict__ amask, const float* __restrict__ maskadd,
    unsigned short* __restrict__ attnw)
{
  const int tid = threadIdx.x;
  const int wave = tid >> 6, lane = tid & 63;
  const int quad = lane >> 4, l16 = lane & 15;
  const int qt = blockIdx.x, bh = blockIdx.y;
  const int b = bh >> 4, h = bh & 15;
  const int qbase = qt * 64 + wave * 16;

  const unsigned short* qh = qw + (size_t)bh * (S_ * D_);
  const unsigned short* kh = kw + (size_t)bh * (S_ * D_);
  const unsigned short* vh = vw + (size_t)bh * (S_ * D_);
  const float* biasb = bias + (size_t)bh * ((size_t)S_ * S_);
  const float* madd = maskadd + b * S_;

  __shared__ unsigned short P_lds[4 * 16 * 72];   // per-wave 16x64, rows padded to 72
  unsigned short* Pw = &P_lds[wave * (16 * 72)];

  // Q A-frags in registers for the whole kernel (lane m = l16, k = quad*8+j)
  bf16x8 aQ0 = *(const bf16x8*)(qh + (size_t)(qbase + l16) * 64 + quad * 8);
  bf16x8 aQ1 = *(const bf16x8*)(qh + (size_t)(qbase + l16) * 64 + 32 + quad * 8);

  floatx4 z = {0.f, 0.f, 0.f, 0.f};
  floatx4 oacc[4] = {z, z, z, z};                  // 16 q rows x 64 d
  float m_run[4], l_run[4];
  for (int r = 0; r < 4; ++r) { m_run[r] = -__builtin_inff(); l_run[r] = 0.f; }

  for (int kt = 0; kt < 16; ++kt) {
    const int key0 = kt * 64;
    floatx4 sfr[4] = {z, z, z, z};
    for (int t = 0; t < 4; ++t) {
      const unsigned short* kr = kh + (size_t)(key0 + 16 * t + l16) * 64;
      bf16x8 bK0 = *(const bf16x8*)(kr + quad * 8);
      bf16x8 bK1 = *(const bf16x8*)(kr + 32 + quad * 8);
      sfr[t] = mfma16x16x32(aQ0, bK0, sfr[t]);
      sfr[t] = mfma16x16x32(aQ1, bK1, sfr[t]);
    }
    float mk[4];
    for (int t = 0; t < 4; ++t) mk[t] = madd[key0 + 16 * t + l16];
    float sv[4][4];
    for (int r = 0; r < 4; ++r) {
      int row = qbase + quad * 4 + r;
      const float* brow = biasb + (size_t)row * S_ + key0;
      const float* arow = amask + (size_t)row * S_ + key0;
      for (int t = 0; t < 4; ++t)
        sv[t][r] = sfr[t][r] + brow[16 * t + l16] + arow[16 * t + l16] + mk[t];
    }
    for (int r = 0; r < 4; ++r) {
      float rm = fmaxf(fmaxf(sv[0][r], sv[1][r]), fmaxf(sv[2][r], sv[3][r]));
      rm = fmaxf(rm, __shfl_xor(rm, 1));
      rm = fmaxf(rm, __shfl_xor(rm, 2));
      rm = fmaxf(rm, __shfl_xor(rm, 4));
      rm = fmaxf(rm, __shfl_xor(rm, 8));
      float mnew = fmaxf(m_run[r], rm);            // always finite (>= -FLT_MAX)
      float alpha = __expf(m_run[r] - mnew);       // first tile: exp(-inf)=0
      float psum = 0.f;
      for (int t = 0; t < 4; ++t) {
        float p = __expf(sv[t][r] - mnew);
        psum += p;
        Pw[(quad * 4 + r) * 72 + 16 * t + l16] = f2bf(p);
      }
      psum += __shfl_xor(psum, 1);
      psum += __shfl_xor(psum, 2);
      psum += __shfl_xor(psum, 4);
      psum += __shfl_xor(psum, 8);
      l_run[r] = l_run[r] * alpha + psum;
      m_run[r] = mnew;
      oacc[0][r] *= alpha; oacc[1][r] *= alpha; oacc[2][r] *= alpha; oacc[3][r] *= alpha;
    }
    // O += P V  (P re-read from LDS in A-layout; V^T gives contiguous B frags)
    for (int kc = 0; kc < 2; ++kc) {
      bf16x8 aP = *(const bf16x8*)(Pw + l16 * 72 + kc * 32 + quad * 8);
      for (int t = 0; t < 4; ++t) {
        bf16x8 bV = *(const bf16x8*)(vh + (size_t)(16 * t + l16) * 1024 + key0 + kc * 32 + quad * 8);
        oacc[t] = mfma16x16x32(aP, bV, oacc[t]);
      }
    }
  }

  for (int r = 0; r < 4; ++r) {
    int row = qbase + quad * 4 + r;
    float inv = 1.0f / l_run[r];                   // l >= 1 always (max attains exp(0))
    unsigned short* orow = attnw + (size_t)(b * S_ + row) * E_ + h * 64;
    for (int t = 0; t < 4; ++t)
      orow[16 * t + l16] = f2bf(oacc[t][r] * inv);
  }
}

// ---------------------------------------------------------------------------
// Kernel 4: output projection. out = attn @ Wo.T + bo, f32 output.
// Same structure as gemm_qkv; A operand already bf16.
// ---------------------------------------------------------------------------
__global__ __launch_bounds__(256) void gemm_out(
    const unsigned short* __restrict__ Abf, const float* __restrict__ Wo,
    const float* __restrict__ bo, float* __restrict__ out)
{
  const int tid = threadIdx.x;
  const int n0 = blockIdx.x * 128;
  const int m0 = blockIdx.y * 128;
  __shared__ unsigned short As[128 * 40];
  __shared__ unsigned short Bs[128 * 40];
  const int wave = tid >> 6, lane = tid & 63;
  const int quad = lane >> 4, l16 = lane & 15;
  const int mb = (wave >> 1) * 64, nb = (wave & 1) * 64;

  floatx4 z = {0.f, 0.f, 0.f, 0.f};
  floatx4 acc[4][4];
  for (int i = 0; i < 4; ++i) for (int j = 0; j < 4; ++j) acc[i][j] = z;

  for (int ks = 0; ks < 32; ++ks) {
    const int k0 = ks * 32;
    __syncthreads();
    for (int i = tid; i < 1024; i += 256) {
      int row = i >> 3, kq = i & 7;
      *(ushort4*)(&As[row * 40 + kq * 4]) =
          *(const ushort4*)(Abf + (size_t)(m0 + row) * 1024 + k0 + kq * 4);
    }
    for (int i = tid; i < 1024; i += 256) {
      int row = i >> 3, kq = i & 7;
      float4 v = *(const float4*)(Wo + (size_t)(n0 + row) * 1024 + k0 + kq * 4);
      ushort4 u; u.x = f2bf(v.x); u.y = f2bf(v.y); u.z = f2bf(v.z); u.w = f2bf(v.w);
      *(ushort4*)(&Bs[row * 40 + kq * 4]) = u;
    }
    __syncthreads();
    bf16x8 af[4], bfm[4];
    for (int i = 0; i < 4; ++i)
      af[i] = *(const bf16x8*)(&As[(mb + 16 * i + l16) * 40 + quad * 8]);
    for (int j = 0; j < 4; ++j)
      bfm[j] = *(const bf16x8*)(&Bs[(nb + 16 * j + l16) * 40 + quad * 8]);
    for (int i = 0; i < 4; ++i)
      for (int j = 0; j < 4; ++j)
        acc[i][j] = mfma16x16x32(af[i], bfm[j], acc[i][j]);
  }

  for (int i = 0; i < 4; ++i) {
    for (int r = 0; r < 4; ++r) {
      int m = m0 + mb + 16 * i + quad * 4 + r;
      for (int j = 0; j < 4; ++j) {
        int n = n0 + nb + 16 * j + l16;
        out[(size_t)m * 1024 + n] = acc[i][j][r] + bo[n];
      }
    }
  }
}

// ---------------------------------------------------------------------------
// Workspace layout (bytes):
//   [0, 16M)    q   bf16 [B,H,S,D]
//   [16M, 32M)  k   bf16 [B,H,S,D]
//   [32M, 48M)  v^T bf16 [B,H,D,S]
//   [48M, 64M)  attn bf16 [B,S,E]
//   [64M, +32K) maskadd f32 [B,S]
// Total ~67.1 MB.
// ---------------------------------------------------------------------------
extern "C" void kernel_launch(void* const* d_in, const int* in_sizes, int n_in,
                              void* d_out, int out_size, void* d_ws, size_t ws_size,
                              hipStream_t stream) {
  const float* query      = (const float*)d_in[0];
  // d_in[1] (key) and d_in[2] (value) are unused: self-attention projects all from query.
  const float* attn_bias  = (const float*)d_in[3];
  const unsigned int* kpm = (const unsigned int*)d_in[4];
  const float* amask      = (const float*)d_in[5];
  const float* Wq = (const float*)d_in[9];
  const float* bq = (const float*)d_in[10];
  const float* Wk = (const float*)d_in[11];
  const float* bk = (const float*)d_in[12];
  const float* Wv = (const float*)d_in[13];
  const float* bv = (const float*)d_in[14];
  const float* Wo = (const float*)d_in[15];
  const float* bo = (const float*)d_in[16];

  char* ws = (char*)d_ws;
  unsigned short* qw    = (unsigned short*)(ws);
  unsigned short* kw    = (unsigned short*)(ws + (size_t)16777216);
  unsigned short* vw    = (unsigned short*)(ws + (size_t)2 * 16777216);
  unsigned short* attnw = (unsigned short*)(ws + (size_t)3 * 16777216);
  float* maskadd        = (float*)(ws + (size_t)4 * 16777216);

  mask_prep<<<1, 256, 0, stream>>>(kpm, maskadd);
  gemm_qkv<<<dim3(24, 64), 256, 0, stream>>>(query, Wq, Wk, Wv, bq, bk, bv, qw, kw, vw);
  attn_fwd<<<dim3(16, 128), 256, 0, stream>>>(qw, kw, vw, attn_bias, amask, maskadd, attnw);
  gemm_out<<<dim3(8, 64), 256, 0, stream>>>(attnw, Wo, bo, (float*)d_out);
}

// Round 2
// 980.338 us; speedup vs baseline: 1.3932x; 1.3932x over previous
//
#include <hip/hip_runtime.h>

#define B_ 8
#define S_ 1024
#define E_ 1024
#define H_ 16
#define D_ 64

typedef __attribute__((ext_vector_type(8))) short bf16x8;
typedef __attribute__((ext_vector_type(4))) float floatx4;

__device__ __forceinline__ floatx4 mfma16x16x32(bf16x8 a, bf16x8 b, floatx4 c) {
  return __builtin_amdgcn_mfma_f32_16x16x32_bf16(a, b, c, 0, 0, 0);
}

// f32 -> bf16 round-to-nearest-even
__device__ __forceinline__ unsigned short f2bf(float x) {
  unsigned int u = __builtin_bit_cast(unsigned int, x);
  u += 0x7FFFu + ((u >> 16) & 1u);
  return (unsigned short)(u >> 16);
}

// async global->LDS, 16 B per lane; LDS dest = wave-uniform base + lane*16
__device__ __forceinline__ void async16(const unsigned short* g, unsigned short* l) {
  __builtin_amdgcn_global_load_lds(
      (const __attribute__((address_space(1))) void*)g,
      (__attribute__((address_space(3))) void*)l, 16, 0, 0);
}

// ---------------------------------------------------------------------------
// key_padding_mask normalize (encoding-sniffing) -> additive 0 / -FLT_MAX
// ---------------------------------------------------------------------------
__global__ void mask_prep(const unsigned int* __restrict__ mraw, float* __restrict__ maskadd) {
  __shared__ int flagF, flagB;
  const int tid = threadIdx.x;
  if (tid == 0) { flagF = 0; flagB = 0; }
  __syncthreads();
  int lf = 0, lb = 0;
  for (int i = tid; i < 2048; i += 256) {
    unsigned int v = mraw[i];
    if (v == 0x3F800000u) lf = 1;
    else if (v > 1u) lb = 1;
  }
  if (lf) atomicOr(&flagF, 1);
  if (lb) atomicOr(&flagB, 1);
  __syncthreads();
  const unsigned char* mb = (const unsigned char*)mraw;
  const float* mf = (const float*)mraw;
  const int* mi = (const int*)mraw;
  const int fF = flagF, fB = flagB;
  for (int i = tid; i < B_ * S_; i += 256) {
    int pad;
    if (fF)      pad = (mf[i] != 0.0f);
    else if (fB) pad = (mb[i] != 0);
    else         pad = (mi[i] != 0);
    maskadd[i] = pad ? -3.4028234663852886e38f : 0.0f;
  }
}

// ---------------------------------------------------------------------------
// One-time f32 -> bf16 conversion: query (8M) + Wq/Wk/Wv/Wo (1M each)
// ---------------------------------------------------------------------------
__global__ __launch_bounds__(256) void convert_prep(
    const float* __restrict__ q, const float* __restrict__ wq, const float* __restrict__ wk,
    const float* __restrict__ wv, const float* __restrict__ wo,
    unsigned short* __restrict__ xb, unsigned short* __restrict__ wqb,
    unsigned short* __restrict__ wkb, unsigned short* __restrict__ wvb,
    unsigned short* __restrict__ wob)
{
  size_t idx = (size_t)blockIdx.x * 256 + threadIdx.x;   // vec4 index
  const float* src; unsigned short* dst; size_t off;
  if (idx < 2097152)      { src = q;  dst = xb;  off = idx; }
  else if (idx < 2359296) { src = wq; dst = wqb; off = idx - 2097152; }
  else if (idx < 2621440) { src = wk; dst = wkb; off = idx - 2359296; }
  else if (idx < 2883584) { src = wv; dst = wvb; off = idx - 2621440; }
  else                    { src = wo; dst = wob; off = idx - 2883584; }
  float4 v = *(const float4*)(src + off * 4);
  ushort4 u; u.x = f2bf(v.x); u.y = f2bf(v.y); u.z = f2bf(v.z); u.w = f2bf(v.w);
  *(ushort4*)(dst + off * 4) = u;
}

// ---------------------------------------------------------------------------
// m97-style bf16 GEMM core used by both projections.
// A [M x 1024] bf16 row-major, B [N x 1024] bf16 row-major (out = A B^T).
// 128x128 tile, BK=64, global_load_lds width 16, XOR-swizzled LDS
// (chunk' = chunk ^ (row&7)) -> 2-way-only bank aliasing on ds_read_b128.
// ---------------------------------------------------------------------------
__device__ __forceinline__ void gemm_core(
    const unsigned short* __restrict__ A, const unsigned short* __restrict__ Bm,
    int m0, int n0, unsigned short* As, unsigned short* Bs, floatx4 (&acc)[4][4])
{
  const int tid = threadIdx.x;
  const int wave = tid >> 6, lane = tid & 63;
  const int quad = lane >> 4, l16 = lane & 15;
  const int mb = (wave >> 1) * 64, nb = (wave & 1) * 64;
  const int ldrow = lane >> 3;              // 0..7 within 8-row group
  const int gchunk = (lane & 7) ^ ldrow;    // swizzled source chunk

  for (int ks = 0; ks < 16; ++ks) {
    const int k0 = ks * 64;
    __syncthreads();
    for (int is = 0; is < 4; ++is) {
      int issue = wave * 4 + is;
      async16(A + (size_t)(m0 + issue * 8 + ldrow) * 1024 + k0 + gchunk * 8, &As[issue * 512]);
      async16(Bm + (size_t)(n0 + issue * 8 + ldrow) * 1024 + k0 + gchunk * 8, &Bs[issue * 512]);
    }
    __syncthreads();
    for (int kk = 0; kk < 2; ++kk) {
      const int pc = ((quad + 4 * kk) ^ (l16 & 7)) * 8;
      bf16x8 af[4], bfm[4];
      for (int i = 0; i < 4; ++i)
        af[i] = *(const bf16x8*)(&As[(mb + 16 * i + l16) * 64 + pc]);
      for (int j = 0; j < 4; ++j)
        bfm[j] = *(const bf16x8*)(&Bs[(nb + 16 * j + l16) * 64 + pc]);
      for (int i = 0; i < 4; ++i)
        for (int j = 0; j < 4; ++j)
          acc[i][j] = mfma16x16x32(af[i], bfm[j], acc[i][j]);
    }
  }
}

// QKV projection: N-tiles 0..7 -> q (scaled), 8..15 -> k, 16..23 -> v (transposed store)
__global__ __launch_bounds__(256) void gemm_qkv(
    const unsigned short* __restrict__ Xbf,
    const unsigned short* __restrict__ Wqb, const unsigned short* __restrict__ Wkb,
    const unsigned short* __restrict__ Wvb,
    const float* __restrict__ bq, const float* __restrict__ bk, const float* __restrict__ bv,
    unsigned short* __restrict__ qo, unsigned short* __restrict__ ko, unsigned short* __restrict__ vo)
{
  const int n0 = blockIdx.x * 128;
  const int m0 = blockIdx.y * 128;
  const int which = n0 >> 10;
  const int nn0 = n0 & 1023;
  const unsigned short* W = (which == 0) ? Wqb : (which == 1) ? Wkb : Wvb;
  const float* bias = (which == 0) ? bq : (which == 1) ? bk : bv;

  __shared__ unsigned short As[128 * 64];
  __shared__ unsigned short Bs[128 * 64];

  const int lane = threadIdx.x & 63, wave = threadIdx.x >> 6;
  const int quad = lane >> 4, l16 = lane & 15;
  const int mb = (wave >> 1) * 64, nb = (wave & 1) * 64;

  floatx4 z = {0.f, 0.f, 0.f, 0.f};
  floatx4 acc[4][4];
  for (int i = 0; i < 4; ++i) for (int j = 0; j < 4; ++j) acc[i][j] = z;

  gemm_core(Xbf, W, m0, nn0, As, Bs, acc);

  float bv4[4];
  for (int j = 0; j < 4; ++j) bv4[j] = bias[nn0 + nb + 16 * j + l16];

  for (int i = 0; i < 4; ++i) {
    for (int r = 0; r < 4; ++r) {
      int m = m0 + mb + 16 * i + quad * 4 + r;   // C/D row = quad*4+reg
      int bb = m >> 10, s = m & 1023;
      for (int j = 0; j < 4; ++j) {
        int nn = nn0 + nb + 16 * j + l16;        // C/D col = lane&15
        int hh = nn >> 6, d = nn & 63;
        float val = acc[i][j][r] + bv4[j];
        if (which == 0) {
          val *= 0.125f;
          qo[((size_t)(bb * 16 + hh) * 1024 + s) * 64 + d] = f2bf(val);
        } else if (which == 1) {
          ko[((size_t)(bb * 16 + hh) * 1024 + s) * 64 + d] = f2bf(val);
        } else {
          vo[((size_t)(bb * 16 + hh) * 64 + d) * 1024 + s] = f2bf(val);  // v^T
        }
      }
    }
  }
}

// Output projection: out = attn @ Wo.T + bo, f32 out
__global__ __launch_bounds__(256) void gemm_out(
    const unsigned short* __restrict__ Abf, const unsigned short* __restrict__ Wob,
    const float* __restrict__ bo, float* __restrict__ out)
{
  const int n0 = blockIdx.x * 128;
  const int m0 = blockIdx.y * 128;
  __shared__ unsigned short As[128 * 64];
  __shared__ unsigned short Bs[128 * 64];

  const int lane = threadIdx.x & 63, wave = threadIdx.x >> 6;
  const int quad = lane >> 4, l16 = lane & 15;
  const int mb = (wave >> 1) * 64, nb = (wave & 1) * 64;

  floatx4 z = {0.f, 0.f, 0.f, 0.f};
  floatx4 acc[4][4];
  for (int i = 0; i < 4; ++i) for (int j = 0; j < 4; ++j) acc[i][j] = z;

  gemm_core(Abf, Wob, m0, n0, As, Bs, acc);

  for (int i = 0; i < 4; ++i) {
    for (int r = 0; r < 4; ++r) {
      int m = m0 + mb + 16 * i + quad * 4 + r;
      for (int j = 0; j < 4; ++j) {
        int n = n0 + nb + 16 * j + l16;
        out[(size_t)m * 1024 + n] = acc[i][j][r] + bo[n];
      }
    }
  }
}

// ---------------------------------------------------------------------------
// Flash attention, latency-hidden version.
// Per block: 64 q-rows x one bh.  Per k-tile (64 keys):
//  - sc[64][68] f32 = bias + attn_mask + key-mask tile, register-double-buffered
//    (prefetch of kt+1 issued after this tile's K-frag loads -> K's vmcnt waits
//     don't drain the prefetch), used as the MFMA C-initializer.
//  - Vt[64][64] bf16 = V^T tile, XOR-swizzled (2-way-only bank aliasing),
//    shared by all 4 waves (kills the 64-way gather of R1).
//  - online softmax per 16-row wave, P through per-wave LDS (C->A layout).
// ---------------------------------------------------------------------------
__global__ __launch_bounds__(256) void attn_fwd(
    const unsigned short* __restrict__ qw, const unsigned short* __restrict__ kw,
    const unsigned short* __restrict__ vw, const float* __restrict__ bias,
    const float* __restrict__ amask, const float* __restrict__ maskadd,
    unsigned short* __restrict__ attnw)
{
  const int tid = threadIdx.x;
  const int wave = tid >> 6, lane = tid & 63;
  const int quad = lane >> 4, l16 = lane & 15;
  const int qt = blockIdx.x, bh = blockIdx.y;
  const int b = bh >> 4, h = bh & 15;
  const int qbase = qt * 64 + wave * 16;

  const unsigned short* qh = qw + (size_t)bh * (S_ * D_);
  const unsigned short* kh = kw + (size_t)bh * (S_ * D_);
  const unsigned short* vh = vw + (size_t)bh * (S_ * D_);
  const float* biasb = bias + (size_t)bh * ((size_t)S_ * S_) + (size_t)(qt * 64) * S_;
  const float* amrow = amask + (size_t)(qt * 64) * S_;
  const float* madd  = maskadd + b * S_;

  __shared__ float sc[64 * 68];                 // bias tile, +4 pad -> 2-way only
  __shared__ unsigned short Vt[64 * 64];        // V^T tile, XOR-swizzled
  __shared__ unsigned short P_lds[4 * 16 * 72];
  unsigned short* Pw = &P_lds[wave * (16 * 72)];

  // staging index maps
  const int srow = tid >> 4;                    // 0..15 (x4 row-issues)
  const int skc  = tid & 15;                    // 4-key chunk
  const int vrow = tid >> 3;                    // 0..31 (x2 issues) = d row
  const int vchk = tid & 7;                     // physical 8-key chunk

  // Q fragments resident for whole kernel
  bf16x8 aQ0 = *(const bf16x8*)(qh + (size_t)(qbase + l16) * 64 + quad * 8);
  bf16x8 aQ1 = *(const bf16x8*)(qh + (size_t)(qbase + l16) * 64 + 32 + quad * 8);

  float4 pb[4], pa[4], pm;
  bf16x8 pv[2];
  auto load_tile = [&](int key0) {
    pm = *(const float4*)(madd + key0 + skc * 4);
    for (int r4 = 0; r4 < 4; ++r4) {
      pb[r4] = *(const float4*)(biasb + (size_t)(srow + 16 * r4) * S_ + key0 + skc * 4);
      pa[r4] = *(const float4*)(amrow + (size_t)(srow + 16 * r4) * S_ + key0 + skc * 4);
    }
    for (int i2 = 0; i2 < 2; ++i2) {
      int d = vrow + 32 * i2;
      int gc = vchk ^ (d & 7);
      pv[i2] = *(const bf16x8*)(vh + (size_t)d * 1024 + key0 + gc * 8);
    }
  };
  load_tile(0);

  floatx4 zz = {0.f, 0.f, 0.f, 0.f};
  floatx4 oacc[4] = {zz, zz, zz, zz};
  float m_run[4], l_run[4];
  for (int r = 0; r < 4; ++r) { m_run[r] = -__builtin_inff(); l_run[r] = 0.f; }

  for (int kt = 0; kt < 16; ++kt) {
    const int key0 = kt * 64;
    __syncthreads();                            // tile buffers free
    for (int r4 = 0; r4 < 4; ++r4) {
      float4 s;
      s.x = pb[r4].x + pa[r4].x + pm.x;
      s.y = pb[r4].y + pa[r4].y + pm.y;
      s.z = pb[r4].z + pa[r4].z + pm.z;
      s.w = pb[r4].w + pa[r4].w + pm.w;
      *(float4*)(&sc[(srow + 16 * r4) * 68 + skc * 4]) = s;
    }
    for (int i2 = 0; i2 < 2; ++i2)
      *(bf16x8*)(&Vt[(vrow + 32 * i2) * 64 + vchk * 8]) = pv[i2];

    // K fragments for THIS tile (issued before prefetch: their vmcnt waits
    // leave the newer prefetch loads in flight)
    bf16x8 bK0[4], bK1[4];
    for (int t = 0; t < 4; ++t) {
      const unsigned short* kr = kh + (size_t)(key0 + 16 * t + l16) * 64;
      bK0[t] = *(const bf16x8*)(kr + quad * 8);
      bK1[t] = *(const bf16x8*)(kr + 32 + quad * 8);
    }
    if (kt < 15) load_tile(key0 + 64);
    __syncthreads();                            // staged tiles visible

    // scores: C-init from sc, then QK^T
    floatx4 sfr[4];
    for (int t = 0; t < 4; ++t) {
      floatx4 c;
      for (int r = 0; r < 4; ++r)
        c[r] = sc[(wave * 16 + quad * 4 + r) * 68 + 16 * t + l16];
      c = mfma16x16x32(aQ0, bK0[t], c);
      c = mfma16x16x32(aQ1, bK1[t], c);
      sfr[t] = c;
    }
    // online softmax (16-lane quad reductions)
    for (int r = 0; r < 4; ++r) {
      float rm = fmaxf(fmaxf(sfr[0][r], sfr[1][r]), fmaxf(sfr[2][r], sfr[3][r]));
      rm = fmaxf(rm, __shfl_xor(rm, 1));
      rm = fmaxf(rm, __shfl_xor(rm, 2));
      rm = fmaxf(rm, __shfl_xor(rm, 4));
      rm = fmaxf(rm, __shfl_xor(rm, 8));
      float mnew = fmaxf(m_run[r], rm);
      float alpha = __expf(m_run[r] - mnew);
      float psum = 0.f;
      for (int t = 0; t < 4; ++t) {
        float p = __expf(sfr[t][r] - mnew);
        psum += p;
        Pw[(quad * 4 + r) * 72 + 16 * t + l16] = f2bf(p);
      }
      psum += __shfl_xor(psum, 1);
      psum += __shfl_xor(psum, 2);
      psum += __shfl_xor(psum, 4);
      psum += __shfl_xor(psum, 8);
      l_run[r] = l_run[r] * alpha + psum;
      m_run[r] = mnew;
      oacc[0][r] *= alpha; oacc[1][r] *= alpha; oacc[2][r] *= alpha; oacc[3][r] *= alpha;
    }
    // O += P V from LDS (wave-local P: lgkm ordering only, no barrier needed)
    for (int kc = 0; kc < 2; ++kc) {
      bf16x8 aP = *(const bf16x8*)(Pw + l16 * 72 + kc * 32 + quad * 8);
      const int pc = ((kc * 4 + quad) ^ (l16 & 7)) * 8;
      for (int t = 0; t < 4; ++t) {
        bf16x8 bV = *(const bf16x8*)(&Vt[(16 * t + l16) * 64 + pc]);
        oacc[t] = mfma16x16x32(aP, bV, oacc[t]);
      }
    }
  }

  for (int r = 0; r < 4; ++r) {
    int row = qbase + quad * 4 + r;
    float inv = 1.0f / l_run[r];
    unsigned short* orow = attnw + (size_t)(b * S_ + row) * E_ + h * 64;
    for (int t = 0; t < 4; ++t)
      orow[16 * t + l16] = f2bf(oacc[t][r] * inv);
  }
}

// ---------------------------------------------------------------------------
// Workspace layout (bytes):
//   [0,16M) q bf16 | [16M,32M) k bf16 | [32M,48M) v^T bf16
//   [48M,64M) Xbf bf16 (during projections) THEN attn bf16 (time-disjoint)
//   [64M..72M) Wq/Wk/Wv/Wo bf16 (2 MB each) | [72M,+32K) maskadd f32
// ---------------------------------------------------------------------------
extern "C" void kernel_launch(void* const* d_in, const int* in_sizes, int n_in,
                              void* d_out, int out_size, void* d_ws, size_t ws_size,
                              hipStream_t stream) {
  const float* query      = (const float*)d_in[0];
  const float* attn_bias  = (const float*)d_in[3];
  const unsigned int* kpm = (const unsigned int*)d_in[4];
  const float* amask      = (const float*)d_in[5];
  const float* Wq = (const float*)d_in[9];
  const float* bq = (const float*)d_in[10];
  const float* Wk = (const float*)d_in[11];
  const float* bk = (const float*)d_in[12];
  const float* Wv = (const float*)d_in[13];
  const float* bv = (const float*)d_in[14];
  const float* Wo = (const float*)d_in[15];
  const float* bo = (const float*)d_in[16];

  char* ws = (char*)d_ws;
  const size_t MB16 = 16777216;
  unsigned short* qw    = (unsigned short*)(ws);
  unsigned short* kw    = (unsigned short*)(ws + MB16);
  unsigned short* vw    = (unsigned short*)(ws + 2 * MB16);
  unsigned short* xbf   = (unsigned short*)(ws + 3 * MB16);  // aliases attnw (time-disjoint)
  unsigned short* attnw = (unsigned short*)(ws + 3 * MB16);
  unsigned short* wqb   = (unsigned short*)(ws + 4 * MB16);
  unsigned short* wkb   = (unsigned short*)(ws + 4 * MB16 + 2097152);
  unsigned short* wvb   = (unsigned short*)(ws + 4 * MB16 + 2 * 2097152);
  unsigned short* wob   = (unsigned short*)(ws + 4 * MB16 + 3 * 2097152);
  float* maskadd        = (float*)(ws + 4 * MB16 + 4 * 2097152);

  mask_prep<<<1, 256, 0, stream>>>(kpm, maskadd);
  convert_prep<<<12288, 256, 0, stream>>>(query, Wq, Wk, Wv, Wo, xbf, wqb, wkb, wvb, wob);
  gemm_qkv<<<dim3(24, 64), 256, 0, stream>>>(xbf, wqb, wkb, wvb, bq, bk, bv, qw, kw, vw);
  attn_fwd<<<dim3(16, 128), 256, 0, stream>>>(qw, kw, vw, attn_bias, amask, maskadd, attnw);
  gemm_out<<<dim3(8, 64), 256, 0, stream>>>(attnw, wob, bo, (float*)d_out);
}